// Round 2
// 11773.717 us; speedup vs baseline: 1.0134x; 1.0134x over previous
//
#include <hip/hip_runtime.h>
#include <hip/hip_bf16.h>

typedef __hip_bfloat16 bf16;
typedef __attribute__((ext_vector_type(8))) short short8;
typedef __attribute__((ext_vector_type(4))) float f32x4;

#define N_ 8
#define B_ 64
#define T_ 256
#define IN_ 64
#define H_ 512
#define G4_ 2048
#define M_ 512
#define O_ 7

__device__ __forceinline__ float sigf(float x) { return 1.0f / (1.0f + __expf(-x)); }
__device__ __forceinline__ float tanhfast(float x) { return 2.0f / (1.0f + __expf(-2.0f * x)) - 1.0f; }

// ---------------- convert fp32 -> bf16 ----------------
__global__ void cvt_kernel(const float* __restrict__ src, bf16* __restrict__ dst, int n4) {
  for (int i = blockIdx.x * blockDim.x + threadIdx.x; i < n4; i += gridDim.x * blockDim.x) {
    float4 v = ((const float4*)src)[i];
    bf16 t0 = __float2bfloat16(v.x), t1 = __float2bfloat16(v.y);
    bf16 t2 = __float2bfloat16(v.z), t3 = __float2bfloat16(v.w);
    ushort4 o;
    o.x = *(unsigned short*)&t0; o.y = *(unsigned short*)&t1;
    o.z = *(unsigned short*)&t2; o.w = *(unsigned short*)&t3;
    ((ushort4*)dst)[i] = o;
  }
}

// ---------------- K1: z = leaky(x@Win^T + bin)*10 ----------------
__global__ void input_kernel(const float* __restrict__ x, const float* __restrict__ Win,
                             const float* __restrict__ bin, bf16* __restrict__ z) {
  int bid = blockIdx.x;
  int t = bid >> 6;
  int b = bid & 63;
  __shared__ float xr[IN_];
  int tid = threadIdx.x;
  if (tid < IN_) xr[tid] = x[((size_t)b * T_ + t) * IN_ + tid];
  __syncthreads();
  for (int h = tid; h < H_; h += 256) {
    const float* w = Win + (size_t)h * IN_;
    float s = bin[h];
#pragma unroll 16
    for (int i = 0; i < IN_; ++i) s += xr[i] * w[i];
    s = (s > 0.f ? s : 0.2f * s) * 10.f;
    z[((size_t)t * B_ + b) * H_ + h] = __float2bfloat16(s);
  }
}

// ---------------- K2: persistent weight-stationary LSTM scan + fused head ----------------
// 256 blocks x 512 thr. Block (n, ub): 16 hidden/M units of model n.
// Wave w = 2*g + m owns (gate g, matrix m) for BOTH layers; its B-fragments
// live in 64+64 VGPRs for the whole kernel.
// Superstep s: L0(t=s), L1(t=s-1), H1(t=s-2), H2(t=s-3).
// Sync per superstep (per model, 32 blocks):
//   producer: release-STORE superstep number to own padded flag (no contended RMW)
//   consumer: wave 0 polls all 32 flags with RELAXED agent loads (no per-poll
//             buffer_inv), then ONE acquire fence, then __syncthreads.
//   progress guarantee: one acquire fence per 64 spin iterations, in case a
//   relaxed agent load can be served from a stale (non-coherent) L2 line.
// H2 runs between flag-store and poll (barrier shadow); mstage is 4-deep so the
// slot H2(s) reads is only rewritten by H1(s+3), gated by our flag(s+2).
__global__ void __launch_bounds__(512, 2) scan_kernel(
    const bf16* __restrict__ z,
    const bf16* __restrict__ Wih0, const bf16* __restrict__ Whh0,
    const float* __restrict__ bih0, const float* __restrict__ bhh0,
    const bf16* __restrict__ Wih1, const bf16* __restrict__ Whh1,
    const float* __restrict__ bih1, const float* __restrict__ bhh1,
    const bf16* __restrict__ Wh1, const float* __restrict__ bh1,
    const float* __restrict__ Wh2, const float* __restrict__ bh2,
    bf16* __restrict__ h0buf, bf16* __restrict__ h1buf,
    bf16* __restrict__ mstage, float* __restrict__ out,
    unsigned* __restrict__ flags)
{
  __shared__ float S0[8][B_][16];   // 8 wave-slots (gate g: slots 2g + 2g+1)
  __shared__ float S1[8][B_][16];
  __shared__ float c0s[B_ * 16];
  __shared__ float c1s[B_ * 16];

  const int tid = threadIdx.x;
  const int lane = tid & 63;
  const int w = tid >> 6;      // 0..7
  const int m = w & 1;         // 0: ih-matrix, 1: hh-matrix
  const int g = w >> 1;        // gate 0..3 (i,f,g,o)
  const int q = lane >> 4;
  const int cl = lane & 15;
  const int bid = blockIdx.x;
  const int n = bid >> 5;
  const int blk = bid & 31;
  const int ub = blk << 4;

  const size_t NBH = (size_t)N_ * B_ * H_;
  const size_t NBM = (size_t)N_ * B_ * M_;

  // ---- one-time weight preload into registers ----
  const size_t wrow = (size_t)n * G4_ * H_ + (size_t)(g * H_ + ub + cl) * H_ + q * 8;
  const bf16* WL0 = (m == 0 ? Wih0 : Whh0) + wrow;
  const bf16* WL1 = (m == 0 ? Wih1 : Whh1) + wrow;
  short8 wl0[16], wl1[16];
#pragma unroll
  for (int kk = 0; kk < 16; ++kk) {
    wl0[kk] = *(const short8*)(WL0 + kk * 32);
    wl1[kk] = *(const short8*)(WL1 + kk * 32);
  }
  // bias carried by the m==0 wave of each gate
  const int bi = n * G4_ + g * H_ + ub + cl;
  const float bs0 = (m == 0) ? (bih0[bi] + bhh0[bi]) : 0.f;
  const float bs1 = (m == 0) ? (bih1[bi] + bhh1[bi]) : 0.f;
  const float bh1v = bh1[n * M_ + ub + cl];   // H1 bias (waves 0..3 use it)

  for (int e = tid; e < B_ * 16; e += 512) { c0s[e] = 0.f; c1s[e] = 0.f; }

  // per-block flag (64B padded) + model's flag group for polling
  unsigned* myflag   = flags + ((size_t)(n * 32 + blk) << 4);
  unsigned* pollbase = flags + ((size_t)(n * 32) << 4);

  for (int s = 0; s < T_ + 3; ++s) {
    const bool doL0 = (s < T_);
    const bool doL1 = (s >= 1 && s <= T_);
    const bool doH1 = (s >= 2 && s <= T_ + 1);
    const bool doH2 = (s >= 3);

    // ---- L0 MFMA: this wave's (matrix,gate) partial over 4 batch strips ----
    if (doL0) {
      const bf16* A = (m == 0)
          ? z + (size_t)s * B_ * H_
          : h0buf + (size_t)((s & 1) ^ 1) * NBH + (size_t)n * B_ * H_;
#pragma unroll
      for (int strip = 0; strip < 4; ++strip) {
        f32x4 acc = (f32x4){bs0, bs0, bs0, bs0};
        const bf16* Ap = A + (size_t)(strip * 16 + cl) * H_ + q * 8;
#pragma unroll
        for (int kk = 0; kk < 16; ++kk) {
          short8 a = *(const short8*)(Ap + kk * 32);
          acc = __builtin_amdgcn_mfma_f32_16x16x32_bf16(a, wl0[kk], acc, 0, 0, 0);
        }
#pragma unroll
        for (int r = 0; r < 4; ++r) S0[w][strip * 16 + q * 4 + r][cl] = acc[r];
      }
    }
    // ---- L1 MFMA ----
    if (doL1) {
      const int t = s - 1;
      const bf16* A = (m == 0)
          ? h0buf + (size_t)(t & 1) * NBH + (size_t)n * B_ * H_
          : h1buf + (size_t)((t & 1) ^ 1) * NBH + (size_t)n * B_ * H_;
#pragma unroll
      for (int strip = 0; strip < 4; ++strip) {
        f32x4 acc = (f32x4){bs1, bs1, bs1, bs1};
        const bf16* Ap = A + (size_t)(strip * 16 + cl) * H_ + q * 8;
#pragma unroll
        for (int kk = 0; kk < 16; ++kk) {
          short8 a = *(const short8*)(Ap + kk * 32);
          acc = __builtin_amdgcn_mfma_f32_16x16x32_bf16(a, wl1[kk], acc, 0, 0, 0);
        }
#pragma unroll
        for (int r = 0; r < 4; ++r) S1[w][strip * 16 + q * 4 + r][cl] = acc[r];
      }
    }
    // ---- H1: 16 M-units of leaky(h1(s-2)@Wh1^T + bh1), all 64 batches (waves 0..3) ----
    // stays BEFORE the flag-store: its mstage writes must be covered by this
    // superstep's release so H2(s+1) on other blocks sees them.
    if (doH1 && w < 4) {
      const int tH1 = s - 2;
      f32x4 aH = (f32x4){bh1v, bh1v, bh1v, bh1v};
      const bf16* hsrc = h1buf + (size_t)(tH1 & 1) * NBH + (size_t)n * B_ * H_;
      const bf16* w1p = Wh1 + (size_t)n * M_ * H_ + (size_t)(ub + cl) * H_ + q * 8;
      const int ar = (w * 16 + cl) * H_ + q * 8;
      for (int kk = 0; kk < H_; kk += 32) {
        short8 a = *(const short8*)(hsrc + ar + kk);
        short8 b = *(const short8*)(w1p + kk);
        aH = __builtin_amdgcn_mfma_f32_16x16x32_bf16(a, b, aH, 0, 0, 0);
      }
      bf16* msl = mstage + (size_t)(tH1 & 3) * NBM + (size_t)n * B_ * M_;
#pragma unroll
      for (int r = 0; r < 4; ++r) {
        float v = aH[r];
        v = v > 0.f ? v : 0.2f * v;
        msl[(w * 16 + q * 4 + r) * M_ + ub + cl] = __float2bfloat16(v);
      }
    }

    __syncthreads();

    // ---- elementwise: assemble gates (sum ih+hh slots), update c, write h ----
    if (doL0) {
      bf16* h0out = h0buf + (size_t)(s & 1) * NBH + (size_t)n * B_ * H_;
      for (int e = tid; e < B_ * 16; e += 512) {
        int row = e >> 4, ul = e & 15;
        float gi = S0[0][row][ul] + S0[1][row][ul];
        float gf = S0[2][row][ul] + S0[3][row][ul];
        float gg = S0[4][row][ul] + S0[5][row][ul];
        float go = S0[6][row][ul] + S0[7][row][ul];
        float c = c0s[e];
        float cn = sigf(gf) * c + sigf(gi) * tanhfast(gg);
        c0s[e] = cn;
        h0out[row * H_ + ub + ul] = __float2bfloat16(sigf(go) * tanhfast(cn));
      }
    }
    if (doL1) {
      const int t = s - 1;
      bf16* h1out = h1buf + (size_t)(t & 1) * NBH + (size_t)n * B_ * H_;
      for (int e = tid; e < B_ * 16; e += 512) {
        int row = e >> 4, ul = e & 15;
        float gi = S1[0][row][ul] + S1[1][row][ul];
        float gf = S1[2][row][ul] + S1[3][row][ul];
        float gg = S1[4][row][ul] + S1[5][row][ul];
        float go = S1[6][row][ul] + S1[7][row][ul];
        float c = c1s[e];
        float cn = sigf(gf) * c + sigf(gi) * tanhfast(gg);
        c1s[e] = cn;
        h1out[row * H_ + ub + ul] = __float2bfloat16(sigf(go) * tanhfast(cn));
      }
    }

    // drain all threads' h/mstage global writes (syncthreads waits vmcnt(0)),
    // then publish: ONE release store per block (flushes dirty lines to the
    // coherence point), no contended RMW.
    __syncthreads();
    if (tid == 0)
      __hip_atomic_store(myflag, (unsigned)(s + 1), __ATOMIC_RELEASE,
                         __HIP_MEMORY_SCOPE_AGENT);

    // ---- H2 in the barrier shadow: 2 batches x 7 outputs, dot over M=512 ----
    // reads mstage slot (tH2 & 3), written+released at superstep s-1 and
    // observed via the s-1 poll; next writer of this slot is H1(s+3),
    // gated by our flag(s+2) which we haven't posted yet -> race-free.
    if (doH2 && w < 2) {
      const int tH2 = s - 3;
      const int b = blk * 2 + w;
      const int o = lane & 7;
      const int oc = o < 7 ? o : 0;
      const int mc = (lane >> 3) * 64;
      const bf16* ms = mstage + (size_t)(tH2 & 3) * NBM + ((size_t)n * B_ + b) * M_ + mc;
      const float* w2p = Wh2 + (size_t)n * O_ * M_ + (size_t)oc * M_ + mc;
      float p = 0.f;
#pragma unroll
      for (int j = 0; j < 64; j += 8) {
        short8 av = *(const short8*)(ms + j);
        const bf16* ae = (const bf16*)&av;
        float4 w0 = *(const float4*)(w2p + j);
        float4 w1 = *(const float4*)(w2p + j + 4);
        p += (float)ae[0] * w0.x + (float)ae[1] * w0.y + (float)ae[2] * w0.z + (float)ae[3] * w0.w
           + (float)ae[4] * w1.x + (float)ae[5] * w1.y + (float)ae[6] * w1.z + (float)ae[7] * w1.w;
      }
      p += __shfl_xor(p, 8, 64);
      p += __shfl_xor(p, 16, 64);
      p += __shfl_xor(p, 32, 64);
      if (lane < 7) {
        p += bh2[n * O_ + o];
        out[(((size_t)n * B_ + b) * T_ + tH2) * O_ + o] = p;
      }
    }

    // ---- consumer: wave 0 polls all 32 model flags with RELAXED loads ----
    // then ONE acquire fence for the whole block, then barrier.
    // Progress hardening: periodic acquire fence while spinning (invalidates
    // any stale cached copy -> guaranteed eventual observation).
    if (w == 0) {
      const unsigned tgt = (unsigned)(s + 1);
      unsigned* fp = pollbase + ((size_t)(lane & 31) << 4);
      int spins = 0;
      while (__hip_atomic_load(fp, __ATOMIC_RELAXED, __HIP_MEMORY_SCOPE_AGENT) < tgt) {
        __builtin_amdgcn_s_sleep(2);
        if (++spins >= 64) {
          spins = 0;
          __builtin_amdgcn_fence(__ATOMIC_ACQUIRE, "agent");
        }
      }
      __builtin_amdgcn_fence(__ATOMIC_ACQUIRE, "agent");
    }
    __syncthreads();
  }
}

extern "C" void kernel_launch(void* const* d_in, const int* in_sizes, int n_in,
                              void* d_out, int out_size, void* d_ws, size_t ws_size,
                              hipStream_t stream) {
  (void)in_sizes; (void)n_in; (void)out_size; (void)ws_size;
  const float* x    = (const float*)d_in[0];
  const float* Win  = (const float*)d_in[1];
  const float* bin  = (const float*)d_in[2];
  const float* Wih0 = (const float*)d_in[3];
  const float* Whh0 = (const float*)d_in[4];
  const float* bih0 = (const float*)d_in[5];
  const float* bhh0 = (const float*)d_in[6];
  const float* Wih1 = (const float*)d_in[7];
  const float* Whh1 = (const float*)d_in[8];
  const float* bih1 = (const float*)d_in[9];
  const float* bhh1 = (const float*)d_in[10];
  const float* Wh1  = (const float*)d_in[11];
  const float* bh1  = (const float*)d_in[12];
  const float* Wh2  = (const float*)d_in[13];
  const float* bh2  = (const float*)d_in[14];

  const size_t WLSTM = (size_t)N_ * G4_ * H_;
  const size_t WH1   = (size_t)N_ * M_ * H_;

  char* ws = (char*)d_ws;
  size_t off = 0;
  bf16* z      = (bf16*)(ws + off); off += (size_t)T_ * B_ * H_ * sizeof(bf16);
  bf16* Wih0b  = (bf16*)(ws + off); off += WLSTM * sizeof(bf16);
  bf16* Whh0b  = (bf16*)(ws + off); off += WLSTM * sizeof(bf16);
  bf16* Wih1b  = (bf16*)(ws + off); off += WLSTM * sizeof(bf16);
  bf16* Whh1b  = (bf16*)(ws + off); off += WLSTM * sizeof(bf16);
  bf16* Wh1b   = (bf16*)(ws + off); off += WH1 * sizeof(bf16);
  bf16* h0buf  = (bf16*)(ws + off); off += 2 * (size_t)N_ * B_ * H_ * sizeof(bf16);
  bf16* h1buf  = (bf16*)(ws + off); off += 2 * (size_t)N_ * B_ * H_ * sizeof(bf16);
  bf16* mstage = (bf16*)(ws + off); off += 4 * (size_t)N_ * B_ * M_ * sizeof(bf16);
  unsigned* flags = (unsigned*)(ws + off); off += (size_t)N_ * 32 * 16 * sizeof(unsigned);

  // zero h/m state + flags (contiguous span)
  hipMemsetAsync(h0buf, 0, (char*)(flags + (size_t)N_ * 32 * 16) - (char*)h0buf, stream);

  cvt_kernel<<<dim3(2048), dim3(256), 0, stream>>>(Wih0, Wih0b, (int)(WLSTM / 4));
  cvt_kernel<<<dim3(2048), dim3(256), 0, stream>>>(Whh0, Whh0b, (int)(WLSTM / 4));
  cvt_kernel<<<dim3(2048), dim3(256), 0, stream>>>(Wih1, Wih1b, (int)(WLSTM / 4));
  cvt_kernel<<<dim3(2048), dim3(256), 0, stream>>>(Whh1, Whh1b, (int)(WLSTM / 4));
  cvt_kernel<<<dim3(1024), dim3(256), 0, stream>>>(Wh1, Wh1b, (int)(WH1 / 4));

  input_kernel<<<dim3(T_ * B_), dim3(256), 0, stream>>>(x, Win, bin, z);

  scan_kernel<<<dim3(256), dim3(512), 0, stream>>>(
      z, Wih0b, Whh0b, bih0, bhh0, Wih1b, Whh1b, bih1, bhh1,
      Wh1b, bh1, Wh2, bh2, h0buf, h1buf, mstage, (float*)d_out, flags);
}

// Round 3
// 9581.222 us; speedup vs baseline: 1.2453x; 1.2288x over previous
//
#include <hip/hip_runtime.h>
#include <hip/hip_bf16.h>

typedef __hip_bfloat16 bf16;
typedef __attribute__((ext_vector_type(8))) short short8;
typedef __attribute__((ext_vector_type(4))) float f32x4;

#define N_ 8
#define B_ 64
#define T_ 256
#define IN_ 64
#define H_ 512
#define G4_ 2048
#define M_ 512
#define O_ 7

__device__ __forceinline__ float sigf(float x) { return 1.0f / (1.0f + __expf(-x)); }
__device__ __forceinline__ float tanhfast(float x) { return 2.0f / (1.0f + __expf(-2.0f * x)) - 1.0f; }

// ---------------- convert fp32 -> bf16 ----------------
__global__ void cvt_kernel(const float* __restrict__ src, bf16* __restrict__ dst, int n4) {
  for (int i = blockIdx.x * blockDim.x + threadIdx.x; i < n4; i += gridDim.x * blockDim.x) {
    float4 v = ((const float4*)src)[i];
    bf16 t0 = __float2bfloat16(v.x), t1 = __float2bfloat16(v.y);
    bf16 t2 = __float2bfloat16(v.z), t3 = __float2bfloat16(v.w);
    ushort4 o;
    o.x = *(unsigned short*)&t0; o.y = *(unsigned short*)&t1;
    o.z = *(unsigned short*)&t2; o.w = *(unsigned short*)&t3;
    ((ushort4*)dst)[i] = o;
  }
}

// ---------------- K1: z = leaky(x@Win^T + bin)*10 ----------------
__global__ void input_kernel(const float* __restrict__ x, const float* __restrict__ Win,
                             const float* __restrict__ bin, bf16* __restrict__ z) {
  int bid = blockIdx.x;
  int t = bid >> 6;
  int b = bid & 63;
  __shared__ float xr[IN_];
  int tid = threadIdx.x;
  if (tid < IN_) xr[tid] = x[((size_t)b * T_ + t) * IN_ + tid];
  __syncthreads();
  for (int h = tid; h < H_; h += 256) {
    const float* w = Win + (size_t)h * IN_;
    float s = bin[h];
#pragma unroll 16
    for (int i = 0; i < IN_; ++i) s += xr[i] * w[i];
    s = (s > 0.f ? s : 0.2f * s) * 10.f;
    z[((size_t)t * B_ + b) * H_ + h] = __float2bfloat16(s);
  }
}

// ---------------- K2: persistent weight-stationary LSTM scan + fused head ----------------
// 256 blocks x 512 thr. Block (n, ub): 16 hidden/M units of model n.
// Wave w = 2*g + m owns (gate g, matrix m) for BOTH layers; weights in VGPRs.
// Superstep s: L0(t=s), L1(t=s-1), H1(t=s-2), H2(t=s-3).
//
// KEY CHANGE vs prior round: NO buffer_wbl2 anywhere. R0 (acquire-RMW barrier)
// and R2 (release-store barrier) were within 1.5% of each other at 45us/superstep
// with MFMA+VALU ~8% busy -> the shared agent-scope RELEASE (wbl2 L2 tag sweep,
// serialized per XCD across 32 blocks) is the suspected floor.
//   - cross-block data (h0/h1/mstage) is now written with RELAXED agent-scope
//     atomic dword stores: sc1 write-through to MALL, L2 never holds it dirty,
//     so no flush is needed for visibility.
//   - flag store is RELAXED (prior __syncthreads drains vmcnt(0) of all waves'
//     sc1 stores; flag and data share the XCD->MALL path).
//   - readers keep ONE flash acquire fence (buffer_inv: cheap, evidence: R0's
//     per-poll invs were free) per superstep, then normal cached vector loads
//     pull fresh lines into L2 and the 8-wave re-reads hit.
__global__ void __launch_bounds__(512, 2) scan_kernel(
    const bf16* __restrict__ z,
    const bf16* __restrict__ Wih0, const bf16* __restrict__ Whh0,
    const float* __restrict__ bih0, const float* __restrict__ bhh0,
    const bf16* __restrict__ Wih1, const bf16* __restrict__ Whh1,
    const float* __restrict__ bih1, const float* __restrict__ bhh1,
    const bf16* __restrict__ Wh1, const float* __restrict__ bh1,
    const float* __restrict__ Wh2, const float* __restrict__ bh2,
    bf16* __restrict__ h0buf, bf16* __restrict__ h1buf,
    bf16* __restrict__ mstage, float* __restrict__ out,
    unsigned* __restrict__ flags)
{
  __shared__ float S0[8][B_][16];   // 8 wave-slots (gate g: slots 2g + 2g+1)
  __shared__ float S1[8][B_][16];
  __shared__ float c0s[B_ * 16];
  __shared__ float c1s[B_ * 16];

  const int tid = threadIdx.x;
  const int lane = tid & 63;
  const int w = tid >> 6;      // 0..7
  const int m = w & 1;         // 0: ih-matrix, 1: hh-matrix
  const int g = w >> 1;        // gate 0..3 (i,f,g,o)
  const int q = lane >> 4;
  const int cl = lane & 15;
  const int bid = blockIdx.x;
  const int n = bid >> 5;
  const int blk = bid & 31;
  const int ub = blk << 4;

  const size_t NBH = (size_t)N_ * B_ * H_;
  const size_t NBM = (size_t)N_ * B_ * M_;

  // ---- one-time weight preload into registers ----
  const size_t wrow = (size_t)n * G4_ * H_ + (size_t)(g * H_ + ub + cl) * H_ + q * 8;
  const bf16* WL0 = (m == 0 ? Wih0 : Whh0) + wrow;
  const bf16* WL1 = (m == 0 ? Wih1 : Whh1) + wrow;
  short8 wl0[16], wl1[16];
#pragma unroll
  for (int kk = 0; kk < 16; ++kk) {
    wl0[kk] = *(const short8*)(WL0 + kk * 32);
    wl1[kk] = *(const short8*)(WL1 + kk * 32);
  }
  // bias carried by the m==0 wave of each gate
  const int bi = n * G4_ + g * H_ + ub + cl;
  const float bs0 = (m == 0) ? (bih0[bi] + bhh0[bi]) : 0.f;
  const float bs1 = (m == 0) ? (bih1[bi] + bhh1[bi]) : 0.f;
  const float bh1v = bh1[n * M_ + ub + cl];   // H1 bias (waves 0..3 use it)

  for (int e = tid; e < B_ * 16; e += 512) { c0s[e] = 0.f; c1s[e] = 0.f; }

  // per-block flag (64B padded) + model's flag group for polling
  unsigned* myflag   = flags + ((size_t)(n * 32 + blk) << 4);
  unsigned* pollbase = flags + ((size_t)(n * 32) << 4);

  for (int s = 0; s < T_ + 3; ++s) {
    const bool doL0 = (s < T_);
    const bool doL1 = (s >= 1 && s <= T_);
    const bool doH1 = (s >= 2 && s <= T_ + 1);
    const bool doH2 = (s >= 3);

    // ---- L0 MFMA: this wave's (matrix,gate) partial over 4 batch strips ----
    if (doL0) {
      const bf16* A = (m == 0)
          ? z + (size_t)s * B_ * H_
          : h0buf + (size_t)((s & 1) ^ 1) * NBH + (size_t)n * B_ * H_;
#pragma unroll
      for (int strip = 0; strip < 4; ++strip) {
        f32x4 acc = (f32x4){bs0, bs0, bs0, bs0};
        const bf16* Ap = A + (size_t)(strip * 16 + cl) * H_ + q * 8;
#pragma unroll
        for (int kk = 0; kk < 16; ++kk) {
          short8 a = *(const short8*)(Ap + kk * 32);
          acc = __builtin_amdgcn_mfma_f32_16x16x32_bf16(a, wl0[kk], acc, 0, 0, 0);
        }
#pragma unroll
        for (int r = 0; r < 4; ++r) S0[w][strip * 16 + q * 4 + r][cl] = acc[r];
      }
    }
    // ---- L1 MFMA ----
    if (doL1) {
      const int t = s - 1;
      const bf16* A = (m == 0)
          ? h0buf + (size_t)(t & 1) * NBH + (size_t)n * B_ * H_
          : h1buf + (size_t)((t & 1) ^ 1) * NBH + (size_t)n * B_ * H_;
#pragma unroll
      for (int strip = 0; strip < 4; ++strip) {
        f32x4 acc = (f32x4){bs1, bs1, bs1, bs1};
        const bf16* Ap = A + (size_t)(strip * 16 + cl) * H_ + q * 8;
#pragma unroll
        for (int kk = 0; kk < 16; ++kk) {
          short8 a = *(const short8*)(Ap + kk * 32);
          acc = __builtin_amdgcn_mfma_f32_16x16x32_bf16(a, wl1[kk], acc, 0, 0, 0);
        }
#pragma unroll
        for (int r = 0; r < 4; ++r) S1[w][strip * 16 + q * 4 + r][cl] = acc[r];
      }
    }
    // ---- H1: 16 M-units of leaky(h1(s-2)@Wh1^T + bh1), all 64 batches (waves 0..3) ----
    // mstage written via sc1 write-through dword stores (packed bf16 pairs).
    if (doH1 && w < 4) {
      const int tH1 = s - 2;
      f32x4 aH = (f32x4){bh1v, bh1v, bh1v, bh1v};
      const bf16* hsrc = h1buf + (size_t)(tH1 & 1) * NBH + (size_t)n * B_ * H_;
      const bf16* w1p = Wh1 + (size_t)n * M_ * H_ + (size_t)(ub + cl) * H_ + q * 8;
      const int ar = (w * 16 + cl) * H_ + q * 8;
      for (int kk = 0; kk < H_; kk += 32) {
        short8 a = *(const short8*)(hsrc + ar + kk);
        short8 b = *(const short8*)(w1p + kk);
        aH = __builtin_amdgcn_mfma_f32_16x16x32_bf16(a, b, aH, 0, 0, 0);
      }
      bf16* msl = mstage + (size_t)(tH1 & 3) * NBM + (size_t)n * B_ * M_;
#pragma unroll
      for (int r = 0; r < 4; ++r) {
        float v = aH[r];
        v = v > 0.f ? v : 0.2f * v;
        bf16 vb = __float2bfloat16(v);
        unsigned hb = *(unsigned short*)&vb;
        unsigned nb = (unsigned)__shfl_xor((int)hb, 1, 64);  // partner lane cl^1
        if (!(cl & 1)) {
          unsigned word = hb | (nb << 16);
          __hip_atomic_store((unsigned*)(msl + (w * 16 + q * 4 + r) * M_ + ub + cl),
                             word, __ATOMIC_RELAXED, __HIP_MEMORY_SCOPE_AGENT);
        }
      }
    }

    __syncthreads();

    // ---- elementwise: assemble gates (sum ih+hh slots), update c, write h ----
    // h written via sc1 write-through dword stores (packed bf16 pairs):
    // no dirty L2 lines -> no wbl2 needed for cross-XCD visibility.
    if (doL0) {
      bf16* h0out = h0buf + (size_t)(s & 1) * NBH + (size_t)n * B_ * H_;
      for (int e = tid; e < B_ * 16; e += 512) {
        int row = e >> 4, ul = e & 15;
        float gi = S0[0][row][ul] + S0[1][row][ul];
        float gf = S0[2][row][ul] + S0[3][row][ul];
        float gg = S0[4][row][ul] + S0[5][row][ul];
        float go = S0[6][row][ul] + S0[7][row][ul];
        float c = c0s[e];
        float cn = sigf(gf) * c + sigf(gi) * tanhfast(gg);
        c0s[e] = cn;
        float hv = sigf(go) * tanhfast(cn);
        bf16 hb16 = __float2bfloat16(hv);
        unsigned hb = *(unsigned short*)&hb16;
        unsigned nb = (unsigned)__shfl_xor((int)hb, 1, 64);  // partner tid^1 = ul^1
        if (!(ul & 1)) {
          unsigned word = hb | (nb << 16);
          __hip_atomic_store((unsigned*)(h0out + row * H_ + ub + ul), word,
                             __ATOMIC_RELAXED, __HIP_MEMORY_SCOPE_AGENT);
        }
      }
    }
    if (doL1) {
      const int t = s - 1;
      bf16* h1out = h1buf + (size_t)(t & 1) * NBH + (size_t)n * B_ * H_;
      for (int e = tid; e < B_ * 16; e += 512) {
        int row = e >> 4, ul = e & 15;
        float gi = S1[0][row][ul] + S1[1][row][ul];
        float gf = S1[2][row][ul] + S1[3][row][ul];
        float gg = S1[4][row][ul] + S1[5][row][ul];
        float go = S1[6][row][ul] + S1[7][row][ul];
        float c = c1s[e];
        float cn = sigf(gf) * c + sigf(gi) * tanhfast(gg);
        c1s[e] = cn;
        float hv = sigf(go) * tanhfast(cn);
        bf16 hb16 = __float2bfloat16(hv);
        unsigned hb = *(unsigned short*)&hb16;
        unsigned nb = (unsigned)__shfl_xor((int)hb, 1, 64);
        if (!(ul & 1)) {
          unsigned word = hb | (nb << 16);
          __hip_atomic_store((unsigned*)(h1out + row * H_ + ub + ul), word,
                             __ATOMIC_RELAXED, __HIP_MEMORY_SCOPE_AGENT);
        }
      }
    }

    // __syncthreads drains vmcnt(0) across all waves -> every sc1 data store
    // has reached the coherence point (or at least entered the same ordered
    // XCD->MALL path) before the flag store issues. RELAXED flag store: no wbl2.
    __syncthreads();
    if (tid == 0)
      __hip_atomic_store(myflag, (unsigned)(s + 1), __ATOMIC_RELAXED,
                         __HIP_MEMORY_SCOPE_AGENT);

    // ---- H2 in the barrier shadow: 2 batches x 7 outputs, dot over M=512 ----
    // reads mstage slot (tH2 & 3), published at superstep s-1 and observed via
    // the s-1 acquire fence; next writer is H1(s+3), gated by our flag(s+2).
    if (doH2 && w < 2) {
      const int tH2 = s - 3;
      const int b = blk * 2 + w;
      const int o = lane & 7;
      const int oc = o < 7 ? o : 0;
      const int mc = (lane >> 3) * 64;
      const bf16* ms = mstage + (size_t)(tH2 & 3) * NBM + ((size_t)n * B_ + b) * M_ + mc;
      const float* w2p = Wh2 + (size_t)n * O_ * M_ + (size_t)oc * M_ + mc;
      float p = 0.f;
#pragma unroll
      for (int j = 0; j < 64; j += 8) {
        short8 av = *(const short8*)(ms + j);
        const bf16* ae = (const bf16*)&av;
        float4 w0 = *(const float4*)(w2p + j);
        float4 w1 = *(const float4*)(w2p + j + 4);
        p += (float)ae[0] * w0.x + (float)ae[1] * w0.y + (float)ae[2] * w0.z + (float)ae[3] * w0.w
           + (float)ae[4] * w1.x + (float)ae[5] * w1.y + (float)ae[6] * w1.z + (float)ae[7] * w1.w;
      }
      p += __shfl_xor(p, 8, 64);
      p += __shfl_xor(p, 16, 64);
      p += __shfl_xor(p, 32, 64);
      if (lane < 7) {
        p += bh2[n * O_ + o];
        out[(((size_t)n * B_ + b) * T_ + tH2) * O_ + o] = p;
      }
    }

    // ---- consumer: wave 0 polls all 32 model flags with RELAXED loads ----
    // then ONE flash acquire fence (buffer_inv: cheap) for the whole block,
    // then barrier. The fence is load-bearing now: it invalidates stale L1/L2
    // lines so next superstep's cached A-loads pull fresh sc1-written data.
    if (w == 0) {
      const unsigned tgt = (unsigned)(s + 1);
      unsigned* fp = pollbase + ((size_t)(lane & 31) << 4);
      int spins = 0;
      while (__hip_atomic_load(fp, __ATOMIC_RELAXED, __HIP_MEMORY_SCOPE_AGENT) < tgt) {
        __builtin_amdgcn_s_sleep(2);
        if (++spins >= 64) {
          spins = 0;
          __builtin_amdgcn_fence(__ATOMIC_ACQUIRE, "agent");
        }
      }
      __builtin_amdgcn_fence(__ATOMIC_ACQUIRE, "agent");
    }
    __syncthreads();
  }
}

extern "C" void kernel_launch(void* const* d_in, const int* in_sizes, int n_in,
                              void* d_out, int out_size, void* d_ws, size_t ws_size,
                              hipStream_t stream) {
  (void)in_sizes; (void)n_in; (void)out_size; (void)ws_size;
  const float* x    = (const float*)d_in[0];
  const float* Win  = (const float*)d_in[1];
  const float* bin  = (const float*)d_in[2];
  const float* Wih0 = (const float*)d_in[3];
  const float* Whh0 = (const float*)d_in[4];
  const float* bih0 = (const float*)d_in[5];
  const float* bhh0 = (const float*)d_in[6];
  const float* Wih1 = (const float*)d_in[7];
  const float* Whh1 = (const float*)d_in[8];
  const float* bih1 = (const float*)d_in[9];
  const float* bhh1 = (const float*)d_in[10];
  const float* Wh1  = (const float*)d_in[11];
  const float* bh1  = (const float*)d_in[12];
  const float* Wh2  = (const float*)d_in[13];
  const float* bh2  = (const float*)d_in[14];

  const size_t WLSTM = (size_t)N_ * G4_ * H_;
  const size_t WH1   = (size_t)N_ * M_ * H_;

  char* ws = (char*)d_ws;
  size_t off = 0;
  bf16* z      = (bf16*)(ws + off); off += (size_t)T_ * B_ * H_ * sizeof(bf16);
  bf16* Wih0b  = (bf16*)(ws + off); off += WLSTM * sizeof(bf16);
  bf16* Whh0b  = (bf16*)(ws + off); off += WLSTM * sizeof(bf16);
  bf16* Wih1b  = (bf16*)(ws + off); off += WLSTM * sizeof(bf16);
  bf16* Whh1b  = (bf16*)(ws + off); off += WLSTM * sizeof(bf16);
  bf16* Wh1b   = (bf16*)(ws + off); off += WH1 * sizeof(bf16);
  bf16* h0buf  = (bf16*)(ws + off); off += 2 * (size_t)N_ * B_ * H_ * sizeof(bf16);
  bf16* h1buf  = (bf16*)(ws + off); off += 2 * (size_t)N_ * B_ * H_ * sizeof(bf16);
  bf16* mstage = (bf16*)(ws + off); off += 4 * (size_t)N_ * B_ * M_ * sizeof(bf16);
  unsigned* flags = (unsigned*)(ws + off); off += (size_t)N_ * 32 * 16 * sizeof(unsigned);

  // zero h/m state + flags (contiguous span)
  hipMemsetAsync(h0buf, 0, (char*)(flags + (size_t)N_ * 32 * 16) - (char*)h0buf, stream);

  cvt_kernel<<<dim3(2048), dim3(256), 0, stream>>>(Wih0, Wih0b, (int)(WLSTM / 4));
  cvt_kernel<<<dim3(2048), dim3(256), 0, stream>>>(Whh0, Whh0b, (int)(WLSTM / 4));
  cvt_kernel<<<dim3(2048), dim3(256), 0, stream>>>(Wih1, Wih1b, (int)(WLSTM / 4));
  cvt_kernel<<<dim3(2048), dim3(256), 0, stream>>>(Whh1, Whh1b, (int)(WLSTM / 4));
  cvt_kernel<<<dim3(1024), dim3(256), 0, stream>>>(Wh1, Wh1b, (int)(WH1 / 4));

  input_kernel<<<dim3(T_ * B_), dim3(256), 0, stream>>>(x, Win, bin, z);

  scan_kernel<<<dim3(256), dim3(512), 0, stream>>>(
      z, Wih0b, Whh0b, bih0, bhh0, Wih1b, Whh1b, bih1, bhh1,
      Wh1b, bh1, Wh2, bh2, h0buf, h1buf, mstage, (float*)d_out, flags);
}

// Round 6
// 9176.137 us; speedup vs baseline: 1.3003x; 1.0441x over previous
//
#include <hip/hip_runtime.h>
#include <hip/hip_bf16.h>

typedef __hip_bfloat16 bf16;
typedef __attribute__((ext_vector_type(8))) short short8;
typedef __attribute__((ext_vector_type(4))) float f32x4;

#define N_ 8
#define B_ 64
#define T_ 256
#define IN_ 64
#define H_ 512
#define G4_ 2048
#define M_ 512
#define O_ 7

__device__ __forceinline__ float sigf(float x) { return 1.0f / (1.0f + __expf(-x)); }
__device__ __forceinline__ float tanhfast(float x) { return 2.0f / (1.0f + __expf(-2.0f * x)) - 1.0f; }

// ---------------- convert fp32 -> bf16 ----------------
__global__ void cvt_kernel(const float* __restrict__ src, bf16* __restrict__ dst, int n4) {
  for (int i = blockIdx.x * blockDim.x + threadIdx.x; i < n4; i += gridDim.x * blockDim.x) {
    float4 v = ((const float4*)src)[i];
    bf16 t0 = __float2bfloat16(v.x), t1 = __float2bfloat16(v.y);
    bf16 t2 = __float2bfloat16(v.z), t3 = __float2bfloat16(v.w);
    ushort4 o;
    o.x = *(unsigned short*)&t0; o.y = *(unsigned short*)&t1;
    o.z = *(unsigned short*)&t2; o.w = *(unsigned short*)&t3;
    ((ushort4*)dst)[i] = o;
  }
}

// ---------------- K1: z = leaky(x@Win^T + bin)*10 ----------------
__global__ void input_kernel(const float* __restrict__ x, const float* __restrict__ Win,
                             const float* __restrict__ bin, bf16* __restrict__ z) {
  int bid = blockIdx.x;
  int t = bid >> 6;
  int b = bid & 63;
  __shared__ float xr[IN_];
  int tid = threadIdx.x;
  if (tid < IN_) xr[tid] = x[((size_t)b * T_ + t) * IN_ + tid];
  __syncthreads();
  for (int h = tid; h < H_; h += 256) {
    const float* w = Win + (size_t)h * IN_;
    float s = bin[h];
#pragma unroll 16
    for (int i = 0; i < IN_; ++i) s += xr[i] * w[i];
    s = (s > 0.f ? s : 0.2f * s) * 10.f;
    z[((size_t)t * B_ + b) * H_ + h] = __float2bfloat16(s);
  }
}

// ---------------- K2: persistent weight-stationary LSTM scan + fused head ----------------
// 256 blocks x 512 thr, 1 block/CU. Block (n, ub): 16 hidden/M units of model n.
// Wave w = 2*g + m owns (gate g, matrix m) for BOTH layers; weights in VGPRs.
// Superstep s: L0(t=s), L1(t=s-1), H1(t=s-2), H2(t=s-3).
//
// Sync protocol: EXACTLY R3's proven one (sc1 write-through relaxed stores for
// h/mstage, relaxed flag store after vmcnt-draining barrier, relaxed sc1 poll,
// one agent acquire fence per superstep). No XCD detection, no hwreg reads
// (R4/R5's false-positive hazard: wrong XCC_ID read -> write-back fast path
// with cross-XCD readers -> deadlock. Removed entirely.)
//
// NEW vs R3: Wh1 lives in LDS. R3 counters showed FETCH 4.78MB/superstep ~=
// Wh1 (512KB x 8 models) refetched from MALL after every superstep's agent
// acquire fence (L2 flash-inv). Per block Wh1 is only 16KB -> load once into
// LDS at startup (written before scan launch, needs no coherence), H1 reads
// it via ds_read_b128. Row pad +4 bf16 (stride 258 dwords === 2 mod 32)
// spreads the 16 cl-lanes across 16 even banks (<=4-way conflict).
__global__ void __launch_bounds__(512, 2) scan_kernel(
    const bf16* __restrict__ z,
    const bf16* __restrict__ Wih0, const bf16* __restrict__ Whh0,
    const float* __restrict__ bih0, const float* __restrict__ bhh0,
    const bf16* __restrict__ Wih1, const bf16* __restrict__ Whh1,
    const float* __restrict__ bih1, const float* __restrict__ bhh1,
    const bf16* __restrict__ Wh1, const float* __restrict__ bh1,
    const float* __restrict__ Wh2, const float* __restrict__ bh2,
    bf16* __restrict__ h0buf, bf16* __restrict__ h1buf,
    bf16* __restrict__ mstage, float* __restrict__ out,
    unsigned* __restrict__ flags)
{
  __shared__ float S0[8][B_][16];   // 8 wave-slots (gate g: slots 2g + 2g+1)
  __shared__ float S1[8][B_][16];
  __shared__ float c0s[B_ * 16];
  __shared__ float c1s[B_ * 16];
  __shared__ bf16 wh1s[16][H_ + 4]; // block's 16 Wh1 rows, padded (16.1KB)

  const int tid = threadIdx.x;
  const int lane = tid & 63;
  const int w = tid >> 6;      // 0..7
  const int m = w & 1;         // 0: ih-matrix, 1: hh-matrix
  const int g = w >> 1;        // gate 0..3 (i,f,g,o)
  const int q = lane >> 4;
  const int cl = lane & 15;
  const int bid = blockIdx.x;
  const int n = bid >> 5;
  const int blk = bid & 31;
  const int ub = blk << 4;

  const size_t NBH = (size_t)N_ * B_ * H_;
  const size_t NBM = (size_t)N_ * B_ * M_;

  // ---- one-time weight preload into registers ----
  const size_t wrow = (size_t)n * G4_ * H_ + (size_t)(g * H_ + ub + cl) * H_ + q * 8;
  const bf16* WL0 = (m == 0 ? Wih0 : Whh0) + wrow;
  const bf16* WL1 = (m == 0 ? Wih1 : Whh1) + wrow;
  short8 wl0[16], wl1[16];
#pragma unroll
  for (int kk = 0; kk < 16; ++kk) {
    wl0[kk] = *(const short8*)(WL0 + kk * 32);
    wl1[kk] = *(const short8*)(WL1 + kk * 32);
  }
  // bias carried by the m==0 wave of each gate
  const int bi = n * G4_ + g * H_ + ub + cl;
  const float bs0 = (m == 0) ? (bih0[bi] + bhh0[bi]) : 0.f;
  const float bs1 = (m == 0) ? (bih1[bi] + bhh1[bi]) : 0.f;
  const float bh1v = bh1[n * M_ + ub + cl];   // H1 bias (waves 0..3 use it)

  // ---- one-time Wh1 -> LDS (16 rows x 512 cols bf16, 1024 short8 chunks) ----
  {
    const bf16* wsrc = Wh1 + (size_t)n * M_ * H_ + (size_t)ub * H_;
    for (int i = tid; i < 16 * 64; i += 512) {
      int row = i >> 6, c8 = (i & 63) * 8;
      *(short8*)&wh1s[row][c8] = *(const short8*)(wsrc + (size_t)row * H_ + c8);
    }
  }

  for (int e = tid; e < B_ * 16; e += 512) { c0s[e] = 0.f; c1s[e] = 0.f; }
  __syncthreads();   // wh1s + c-state ready

  // per-block flag (64B padded) + model's flag group for polling
  unsigned* myflag   = flags + ((size_t)(n * 32 + blk) << 4);
  unsigned* pollbase = flags + ((size_t)(n * 32) << 4);

  for (int s = 0; s < T_ + 3; ++s) {
    const bool doL0 = (s < T_);
    const bool doL1 = (s >= 1 && s <= T_);
    const bool doH1 = (s >= 2 && s <= T_ + 1);
    const bool doH2 = (s >= 3);

    // ---- L0 MFMA: this wave's (matrix,gate) partial over 4 batch strips ----
    if (doL0) {
      const bf16* A = (m == 0)
          ? z + (size_t)s * B_ * H_
          : h0buf + (size_t)((s & 1) ^ 1) * NBH + (size_t)n * B_ * H_;
#pragma unroll
      for (int strip = 0; strip < 4; ++strip) {
        f32x4 acc = (f32x4){bs0, bs0, bs0, bs0};
        const bf16* Ap = A + (size_t)(strip * 16 + cl) * H_ + q * 8;
#pragma unroll
        for (int kk = 0; kk < 16; ++kk) {
          short8 a = *(const short8*)(Ap + kk * 32);
          acc = __builtin_amdgcn_mfma_f32_16x16x32_bf16(a, wl0[kk], acc, 0, 0, 0);
        }
#pragma unroll
        for (int r = 0; r < 4; ++r) S0[w][strip * 16 + q * 4 + r][cl] = acc[r];
      }
    }
    // ---- L1 MFMA ----
    if (doL1) {
      const int t = s - 1;
      const bf16* A = (m == 0)
          ? h0buf + (size_t)(t & 1) * NBH + (size_t)n * B_ * H_
          : h1buf + (size_t)((t & 1) ^ 1) * NBH + (size_t)n * B_ * H_;
#pragma unroll
      for (int strip = 0; strip < 4; ++strip) {
        f32x4 acc = (f32x4){bs1, bs1, bs1, bs1};
        const bf16* Ap = A + (size_t)(strip * 16 + cl) * H_ + q * 8;
#pragma unroll
        for (int kk = 0; kk < 16; ++kk) {
          short8 a = *(const short8*)(Ap + kk * 32);
          acc = __builtin_amdgcn_mfma_f32_16x16x32_bf16(a, wl1[kk], acc, 0, 0, 0);
        }
#pragma unroll
        for (int r = 0; r < 4; ++r) S1[w][strip * 16 + q * 4 + r][cl] = acc[r];
      }
    }
    // ---- H1: 16 M-units of leaky(h1(s-2)@Wh1^T + bh1), all 64 batches (waves 0..3) ----
    // b-operand now from LDS (wh1s) instead of globally-refetched Wh1.
    if (doH1 && w < 4) {
      const int tH1 = s - 2;
      f32x4 aH = (f32x4){bh1v, bh1v, bh1v, bh1v};
      const bf16* hsrc = h1buf + (size_t)(tH1 & 1) * NBH + (size_t)n * B_ * H_;
      const int ar = (w * 16 + cl) * H_ + q * 8;
      for (int kk = 0; kk < H_; kk += 32) {
        short8 a = *(const short8*)(hsrc + ar + kk);
        short8 b = *(const short8*)&wh1s[cl][q * 8 + kk];
        aH = __builtin_amdgcn_mfma_f32_16x16x32_bf16(a, b, aH, 0, 0, 0);
      }
      bf16* msl = mstage + (size_t)(tH1 & 3) * NBM + (size_t)n * B_ * M_;
#pragma unroll
      for (int r = 0; r < 4; ++r) {
        float v = aH[r];
        v = v > 0.f ? v : 0.2f * v;
        bf16 vb = __float2bfloat16(v);
        unsigned hb = *(unsigned short*)&vb;
        unsigned nb = (unsigned)__shfl_xor((int)hb, 1, 64);  // partner lane cl^1
        if (!(cl & 1)) {
          unsigned word = hb | (nb << 16);
          __hip_atomic_store((unsigned*)(msl + (w * 16 + q * 4 + r) * M_ + ub + cl),
                             word, __ATOMIC_RELAXED, __HIP_MEMORY_SCOPE_AGENT);
        }
      }
    }

    __syncthreads();

    // ---- elementwise: assemble gates (sum ih+hh slots), update c, write h ----
    // h written via sc1 write-through dword stores (packed bf16 pairs):
    // no dirty L2 lines -> no wbl2 needed for cross-XCD visibility.
    if (doL0) {
      bf16* h0out = h0buf + (size_t)(s & 1) * NBH + (size_t)n * B_ * H_;
      for (int e = tid; e < B_ * 16; e += 512) {
        int row = e >> 4, ul = e & 15;
        float gi = S0[0][row][ul] + S0[1][row][ul];
        float gf = S0[2][row][ul] + S0[3][row][ul];
        float gg = S0[4][row][ul] + S0[5][row][ul];
        float go = S0[6][row][ul] + S0[7][row][ul];
        float c = c0s[e];
        float cn = sigf(gf) * c + sigf(gi) * tanhfast(gg);
        c0s[e] = cn;
        float hv = sigf(go) * tanhfast(cn);
        bf16 hb16 = __float2bfloat16(hv);
        unsigned hb = *(unsigned short*)&hb16;
        unsigned nb = (unsigned)__shfl_xor((int)hb, 1, 64);  // partner tid^1 = ul^1
        if (!(ul & 1)) {
          unsigned word = hb | (nb << 16);
          __hip_atomic_store((unsigned*)(h0out + row * H_ + ub + ul), word,
                             __ATOMIC_RELAXED, __HIP_MEMORY_SCOPE_AGENT);
        }
      }
    }
    if (doL1) {
      const int t = s - 1;
      bf16* h1out = h1buf + (size_t)(t & 1) * NBH + (size_t)n * B_ * H_;
      for (int e = tid; e < B_ * 16; e += 512) {
        int row = e >> 4, ul = e & 15;
        float gi = S1[0][row][ul] + S1[1][row][ul];
        float gf = S1[2][row][ul] + S1[3][row][ul];
        float gg = S1[4][row][ul] + S1[5][row][ul];
        float go = S1[6][row][ul] + S1[7][row][ul];
        float c = c1s[e];
        float cn = sigf(gf) * c + sigf(gi) * tanhfast(gg);
        c1s[e] = cn;
        float hv = sigf(go) * tanhfast(cn);
        bf16 hb16 = __float2bfloat16(hv);
        unsigned hb = *(unsigned short*)&hb16;
        unsigned nb = (unsigned)__shfl_xor((int)hb, 1, 64);
        if (!(ul & 1)) {
          unsigned word = hb | (nb << 16);
          __hip_atomic_store((unsigned*)(h1out + row * H_ + ub + ul), word,
                             __ATOMIC_RELAXED, __HIP_MEMORY_SCOPE_AGENT);
        }
      }
    }

    // __syncthreads drains vmcnt(0) across all waves -> every sc1 data store
    // has reached the coherence point before the flag store issues.
    __syncthreads();
    if (tid == 0)
      __hip_atomic_store(myflag, (unsigned)(s + 1), __ATOMIC_RELAXED,
                         __HIP_MEMORY_SCOPE_AGENT);

    // ---- H2 in the barrier shadow: 2 batches x 7 outputs, dot over M=512 ----
    // reads mstage slot (tH2 & 3), published at superstep s-1 and observed via
    // the s-1 acquire fence; next writer is H1(s+3), gated by our flag(s+2).
    if (doH2 && w < 2) {
      const int tH2 = s - 3;
      const int b = blk * 2 + w;
      const int o = lane & 7;
      const int oc = o < 7 ? o : 0;
      const int mc = (lane >> 3) * 64;
      const bf16* ms = mstage + (size_t)(tH2 & 3) * NBM + ((size_t)n * B_ + b) * M_ + mc;
      const float* w2p = Wh2 + (size_t)n * O_ * M_ + (size_t)oc * M_ + mc;
      float p = 0.f;
#pragma unroll
      for (int j = 0; j < 64; j += 8) {
        short8 av = *(const short8*)(ms + j);
        const bf16* ae = (const bf16*)&av;
        float4 w0 = *(const float4*)(w2p + j);
        float4 w1 = *(const float4*)(w2p + j + 4);
        p += (float)ae[0] * w0.x + (float)ae[1] * w0.y + (float)ae[2] * w0.z + (float)ae[3] * w0.w
           + (float)ae[4] * w1.x + (float)ae[5] * w1.y + (float)ae[6] * w1.z + (float)ae[7] * w1.w;
      }
      p += __shfl_xor(p, 8, 64);
      p += __shfl_xor(p, 16, 64);
      p += __shfl_xor(p, 32, 64);
      if (lane < 7) {
        p += bh2[n * O_ + o];
        out[(((size_t)n * B_ + b) * T_ + tH2) * O_ + o] = p;
      }
    }

    // ---- consumer: wave 0 polls all 32 model flags with RELAXED loads ----
    // then ONE flash acquire fence for the whole block, then barrier.
    if (w == 0) {
      const unsigned tgt = (unsigned)(s + 1);
      unsigned* fp = pollbase + ((size_t)(lane & 31) << 4);
      int spins = 0;
      while (__hip_atomic_load(fp, __ATOMIC_RELAXED, __HIP_MEMORY_SCOPE_AGENT) < tgt) {
        __builtin_amdgcn_s_sleep(2);
        if (++spins >= 64) {
          spins = 0;
          __builtin_amdgcn_fence(__ATOMIC_ACQUIRE, "agent");
        }
      }
      __builtin_amdgcn_fence(__ATOMIC_ACQUIRE, "agent");
    }
    __syncthreads();
  }
}

extern "C" void kernel_launch(void* const* d_in, const int* in_sizes, int n_in,
                              void* d_out, int out_size, void* d_ws, size_t ws_size,
                              hipStream_t stream) {
  (void)in_sizes; (void)n_in; (void)out_size; (void)ws_size;
  const float* x    = (const float*)d_in[0];
  const float* Win  = (const float*)d_in[1];
  const float* bin  = (const float*)d_in[2];
  const float* Wih0 = (const float*)d_in[3];
  const float* Whh0 = (const float*)d_in[4];
  const float* bih0 = (const float*)d_in[5];
  const float* bhh0 = (const float*)d_in[6];
  const float* Wih1 = (const float*)d_in[7];
  const float* Whh1 = (const float*)d_in[8];
  const float* bih1 = (const float*)d_in[9];
  const float* bhh1 = (const float*)d_in[10];
  const float* Wh1  = (const float*)d_in[11];
  const float* bh1  = (const float*)d_in[12];
  const float* Wh2  = (const float*)d_in[13];
  const float* bh2  = (const float*)d_in[14];

  const size_t WLSTM = (size_t)N_ * G4_ * H_;
  const size_t WH1   = (size_t)N_ * M_ * H_;
  const size_t NFLAG = (size_t)N_ * 32 * 16;

  char* ws = (char*)d_ws;
  size_t off = 0;
  bf16* z      = (bf16*)(ws + off); off += (size_t)T_ * B_ * H_ * sizeof(bf16);
  bf16* Wih0b  = (bf16*)(ws + off); off += WLSTM * sizeof(bf16);
  bf16* Whh0b  = (bf16*)(ws + off); off += WLSTM * sizeof(bf16);
  bf16* Wih1b  = (bf16*)(ws + off); off += WLSTM * sizeof(bf16);
  bf16* Whh1b  = (bf16*)(ws + off); off += WLSTM * sizeof(bf16);
  bf16* Wh1b   = (bf16*)(ws + off); off += WH1 * sizeof(bf16);
  bf16* h0buf  = (bf16*)(ws + off); off += 2 * (size_t)N_ * B_ * H_ * sizeof(bf16);
  bf16* h1buf  = (bf16*)(ws + off); off += 2 * (size_t)N_ * B_ * H_ * sizeof(bf16);
  bf16* mstage = (bf16*)(ws + off); off += 4 * (size_t)N_ * B_ * M_ * sizeof(bf16);
  unsigned* flags = (unsigned*)(ws + off); off += NFLAG * sizeof(unsigned);

  // zero h/m state + flags (contiguous span)
  hipMemsetAsync(h0buf, 0, (char*)(flags + NFLAG) - (char*)h0buf, stream);

  cvt_kernel<<<dim3(2048), dim3(256), 0, stream>>>(Wih0, Wih0b, (int)(WLSTM / 4));
  cvt_kernel<<<dim3(2048), dim3(256), 0, stream>>>(Whh0, Whh0b, (int)(WLSTM / 4));
  cvt_kernel<<<dim3(2048), dim3(256), 0, stream>>>(Wih1, Wih1b, (int)(WLSTM / 4));
  cvt_kernel<<<dim3(2048), dim3(256), 0, stream>>>(Whh1, Whh1b, (int)(WLSTM / 4));
  cvt_kernel<<<dim3(1024), dim3(256), 0, stream>>>(Wh1, Wh1b, (int)(WH1 / 4));

  input_kernel<<<dim3(T_ * B_), dim3(256), 0, stream>>>(x, Win, bin, z);

  scan_kernel<<<dim3(256), dim3(512), 0, stream>>>(
      z, Wih0b, Whh0b, bih0, bhh0, Wih1b, Whh1b, bih1, bhh1,
      Wh1b, bh1, Wh2, bh2, h0buf, h1buf, mstage, (float*)d_out, flags);
}